// Round 13
// baseline (206.186 us; speedup 1.0000x reference)
//
#include <hip/hip_runtime.h>
#include <hip/hip_bf16.h>
#include <math.h>

typedef _Float16 f16;
typedef _Float16 half8 __attribute__((ext_vector_type(8)));
typedef _Float16 half4 __attribute__((ext_vector_type(4)));
typedef float f32x4 __attribute__((ext_vector_type(4)));

#define DIMC 512
#define HEADS 8
#define HD 64
#define BB 4
#define NN 2048
#define MM (BB*NN)        // 8192
#define NQKV (3*DIMC)     // 1536
#define SCALE 0.125f
#define LOG2E 1.44269504f
#define EPSLN 1e-5f
#define NCHUNK 4

__device__ __forceinline__ void g2l16(const void* g, void* l) {
    __builtin_amdgcn_global_load_lds(
        (const __attribute__((address_space(1))) unsigned int*)g,
        (__attribute__((address_space(3))) unsigned int*)l, 16, 0, 0);
}

// ---------------- prep: LayerNorm (blocks 0..2047) + weight transposes ----------------
__device__ __forceinline__ void ln_rows(const float* __restrict__ x,
                                        const float* __restrict__ gamma,
                                        const float* __restrict__ beta,
                                        f16* __restrict__ xn, int blk) {
    int w = threadIdx.x >> 6;
    int lane = threadIdx.x & 63;
    int row = blk * 4 + w;
    const float* xr = x + (size_t)row * DIMC;
    float4 v0 = ((const float4*)xr)[lane * 2];
    float4 v1 = ((const float4*)xr)[lane * 2 + 1];
    float s = v0.x + v0.y + v0.z + v0.w + v1.x + v1.y + v1.z + v1.w;
#pragma unroll
    for (int off = 1; off < 64; off <<= 1) s += __shfl_xor(s, off);
    float mu = s * (1.0f / DIMC);
    float d0 = v0.x - mu, d1 = v0.y - mu, d2 = v0.z - mu, d3 = v0.w - mu;
    float d4 = v1.x - mu, d5 = v1.y - mu, d6 = v1.z - mu, d7 = v1.w - mu;
    float s2 = d0*d0 + d1*d1 + d2*d2 + d3*d3 + d4*d4 + d5*d5 + d6*d6 + d7*d7;
#pragma unroll
    for (int off = 1; off < 64; off <<= 1) s2 += __shfl_xor(s2, off);
    float rstd = rsqrtf(s2 * (1.0f / DIMC) + EPSLN);
    float4 g0 = ((const float4*)gamma)[lane * 2];
    float4 g1 = ((const float4*)gamma)[lane * 2 + 1];
    float4 b0 = ((const float4*)beta)[lane * 2];
    float4 b1 = ((const float4*)beta)[lane * 2 + 1];
    half8 o;
    o[0] = (f16)(d0 * rstd * g0.x + b0.x);
    o[1] = (f16)(d1 * rstd * g0.y + b0.y);
    o[2] = (f16)(d2 * rstd * g0.z + b0.z);
    o[3] = (f16)(d3 * rstd * g0.w + b0.w);
    o[4] = (f16)(d4 * rstd * g1.x + b1.x);
    o[5] = (f16)(d5 * rstd * g1.y + b1.y);
    o[6] = (f16)(d6 * rstd * g1.z + b1.z);
    o[7] = (f16)(d7 * rstd * g1.w + b1.w);
    ((half8*)(xn + (size_t)row * DIMC))[lane] = o;
}

__device__ __forceinline__ void transp_tile(const float* __restrict__ src,
                                            f16* __restrict__ dst,
                                            int R, int C, int k0, int n0) {
    __shared__ f16 t[32][72];
    int tid = threadIdx.x;
    int rr = tid >> 6, col = tid & 63;
#pragma unroll
    for (int p = 0; p < 8; p++) {
        int r = p * 4 + rr;
        t[r][col] = (f16)src[(size_t)(k0 + r) * C + n0 + col];
    }
    __syncthreads();
    int nl = tid >> 2, kc = (tid & 3) * 8;
    half8 v;
#pragma unroll
    for (int j = 0; j < 8; j++) v[j] = t[kc + j][nl];
    *(half8*)&dst[(size_t)(n0 + nl) * R + k0 + kc] = v;
}

__global__ __launch_bounds__(256) void prep_kernel(const float* __restrict__ x,
                                                   const float* __restrict__ gamma,
                                                   const float* __restrict__ beta,
                                                   const float* __restrict__ wqkv,
                                                   const float* __restrict__ wproj,
                                                   f16* __restrict__ xn,
                                                   f16* __restrict__ wqkvt,
                                                   f16* __restrict__ wprojt) {
    int bid = blockIdx.x;
    if (bid < 2048) {
        ln_rows(x, gamma, beta, xn, bid);
    } else if (bid < 2048 + 384) {
        int b2 = bid - 2048;
        int bx = b2 % 24, by = b2 / 24;
        transp_tile(wqkv, wqkvt, DIMC, NQKV, by * 32, bx * 64);
    } else {
        int b2 = bid - 2048 - 384;
        int bx = b2 % 8, by = b2 / 8;
        transp_tile(wproj, wprojt, DIMC, DIMC, by * 32, bx * 64);
    }
}

// ---------------- shared 128x128 GEMM mainloop (BK=32, g2l16 — R9 proven) ----------------
__device__ __forceinline__ void gemm128_loop(const char* Ag, const char* Bg,
                                             f16* As, f16* Bs, f32x4 (&acc)[4][4]) {
    int tid = threadIdx.x;
    int w = tid >> 6, lane = tid & 63, l15 = lane & 15, quad = lane >> 4;
    int wy = w >> 1, wx = w & 1;
    int off0 = w * 1024 + lane * 16;
    for (int kk = 0; kk < 16; ++kk) {
        __syncthreads();
#pragma unroll
        for (int c = 0; c < 2; ++c) {
            int off = c * 4096 + off0;
            int row = off >> 6, col = off & 63;
            g2l16(Ag + (size_t)row * 1024 + kk * 64 + col, (char*)As + c * 4096 + w * 1024);
            g2l16(Bg + (size_t)row * 1024 + kk * 64 + col, (char*)Bs + c * 4096 + w * 1024);
        }
        __syncthreads();
        half8 af[4], bf[4];
#pragma unroll
        for (int i = 0; i < 4; ++i) {
            af[i] = *(const half8*)((const char*)As + ((wy * 64 + i * 16 + l15) << 6) + quad * 16);
            bf[i] = *(const half8*)((const char*)Bs + ((wx * 64 + i * 16 + l15) << 6) + quad * 16);
        }
#pragma unroll
        for (int i = 0; i < 4; ++i)
#pragma unroll
            for (int j = 0; j < 4; ++j)
                acc[i][j] = __builtin_amdgcn_mfma_f32_16x16x32_f16(af[i], bf[j], acc[i][j], 0, 0, 0);
    }
}

// ---------------- QKV GEMM 128x128; Q/K direct stores, V via LDS transpose ----------------
__global__ __launch_bounds__(256) void gemm_qkv(const f16* __restrict__ xn,
                                                const f16* __restrict__ wt,
                                                f16* __restrict__ qb,
                                                f16* __restrict__ kbuf,
                                                f16* __restrict__ vtb) {
    __shared__ __align__(16) f16 As[128 * 32];
    __shared__ __align__(16) f16 Bs[128 * 32];
    int tid = threadIdx.x;
    int w = tid >> 6, lane = tid & 63, l15 = lane & 15, quad = lane >> 4;
    int wy = w >> 1, wx = w & 1;
    int m0 = blockIdx.y * 128, c0 = blockIdx.x * 128;
    f32x4 acc[4][4] = {};
    gemm128_loop((const char*)(xn + (size_t)m0 * DIMC),
                 (const char*)(wt + (size_t)c0 * DIMC), As, Bs, acc);
    int bx = blockIdx.x;
    if (bx < 8) {
        const float QS = SCALE * LOG2E;
        f16* dst = (bx < 4) ? qb : kbuf;
        float mul = (bx < 4) ? QS : 1.0f;
        int cb = (bx < 4) ? c0 : c0 - DIMC;
#pragma unroll
        for (int i = 0; i < 4; ++i)
#pragma unroll
            for (int j = 0; j < 4; ++j)
#pragma unroll
                for (int r = 0; r < 4; ++r) {
                    int m = m0 + wy * 64 + i * 16 + quad * 4 + r;
                    int c = cb + wx * 64 + j * 16 + l15;
                    int b = m >> 11, n = m & 2047;
                    int h = c >> 6, d = c & 63;
                    dst[(((size_t)(b * HEADS + h)) * NN + n) * HD + d] = (f16)(acc[i][j][r] * mul);
                }
    } else {
        __syncthreads();
        f16* T = (f16*)As + w * 512;
        int cb = c0 - 2 * DIMC;
        int dl = lane >> 2, mp = lane & 3;
#pragma unroll
        for (int i = 0; i < 4; ++i)
#pragma unroll
            for (int j = 0; j < 4; ++j) {
                half4 hv;
#pragma unroll
                for (int r = 0; r < 4; ++r) hv[r] = (f16)acc[i][j][r];
                *(half4*)&T[l15 * 20 + quad * 4] = hv;
                half4 rv = *(half4*)&T[dl * 20 + mp * 4];
                int c = cb + wx * 64 + j * 16 + dl;
                int m = m0 + wy * 64 + i * 16 + mp * 4;
                int b = m >> 11, n = m & 2047;
                int h = c >> 6, d = c & 63;
                *(half4*)&vtb[(((size_t)(b * HEADS + h)) * HD + d) * NN + n] = rv;
            }
    }
}

// ---------------- Flash attention: K-split x4, fixed-base softmax, XCD-swizzled (R11 best) ----------------
__global__ __launch_bounds__(256, 4) void attn_kernel(const f16* __restrict__ qb,
                                                      const f16* __restrict__ kbuf,
                                                      const f16* __restrict__ vtb,
                                                      f16* __restrict__ po,
                                                      float* __restrict__ pl) {
    __shared__ __align__(16) f16 KV[9216];   // Ks[64*72] ++ Vs[64*72]
    f16* Ks = KV;
    f16* Vs = KV + 4608;
    int id = blockIdx.x;
    int xcd = id & 7, slot = id >> 3;
    int g = xcd * 16 + (slot >> 4);          // 0..127 = (chunk, bh)
    int qt4 = slot & 15;                     // q-tile 0..15
    int bh = g & 31;
    int chunk = g >> 5;
    int n0 = qt4 * 128;
    int tid = threadIdx.x, w = tid >> 6, lane = tid & 63, l15 = lane & 15, quad = lane >> 4;
    const f16* Kbase = kbuf + (size_t)bh * NN * HD;
    const f16* Vbase = vtb + (size_t)bh * HD * NN;
    const f16* Qbase = qb + (size_t)bh * NN * HD;
    half8 qf[2][2];
#pragma unroll
    for (int qt = 0; qt < 2; ++qt) {
        const f16* qr = Qbase + (size_t)(n0 + w * 32 + qt * 16 + l15) * HD + quad * 8;
        qf[qt][0] = *(const half8*)qr;
        qf[qt][1] = *(const half8*)(qr + 32);
    }
    f32x4 ot[2][4] = {};
    f32x4 lacc[2] = {};
    half4 ones;
#pragma unroll
    for (int j = 0; j < 4; ++j) ones[j] = (f16)1.0f;
    int srow = tid >> 2, part = (tid & 3) * 16;
    int kbeg = chunk * (NN / NCHUNK);
    half8 kp0, kp1, vp0, vp1;
    {
        const f16* kg = Kbase + (size_t)(kbeg + srow) * HD + part;
        kp0 = ((const half8*)kg)[0]; kp1 = ((const half8*)kg)[1];
        const f16* vg = Vbase + (size_t)srow * NN + kbeg + part;
        vp0 = ((const half8*)vg)[0]; vp1 = ((const half8*)vg)[1];
    }
    for (int it = 0; it < NN / NCHUNK / 64; ++it) {
        __syncthreads();
        *(half8*)&Ks[srow * 72 + part] = kp0;
        *(half8*)&Ks[srow * 72 + part + 8] = kp1;
        *(half8*)&Vs[srow * 72 + part] = vp0;
        *(half8*)&Vs[srow * 72 + part + 8] = vp1;
        __syncthreads();
        if (it < NN / NCHUNK / 64 - 1) {
            int kt0 = kbeg + (it + 1) * 64;
            const f16* kg = Kbase + (size_t)(kt0 + srow) * HD + part;
            kp0 = ((const half8*)kg)[0]; kp1 = ((const half8*)kg)[1];
            const f16* vg = Vbase + (size_t)srow * NN + kt0 + part;
            vp0 = ((const half8*)vg)[0]; vp1 = ((const half8*)vg)[1];
        }
        f32x4 s0[4], s1[4];
#pragma unroll
        for (int kt = 0; kt < 4; ++kt) {
            half8 a0 = *(const half8*)&Ks[(kt * 16 + l15) * 72 + quad * 8];
            half8 a1 = *(const half8*)&Ks[(kt * 16 + l15) * 72 + 32 + quad * 8];
            f32x4 z0 = {};
            z0 = __builtin_amdgcn_mfma_f32_16x16x32_f16(a0, qf[0][0], z0, 0, 0, 0);
            z0 = __builtin_amdgcn_mfma_f32_16x16x32_f16(a1, qf[0][1], z0, 0, 0, 0);
            s0[kt] = z0;
            f32x4 z1 = {};
            z1 = __builtin_amdgcn_mfma_f32_16x16x32_f16(a0, qf[1][0], z1, 0, 0, 0);
            z1 = __builtin_amdgcn_mfma_f32_16x16x32_f16(a1, qf[1][1], z1, 0, 0, 0);
            s1[kt] = z1;
        }
        half4 pb[2][4];
#pragma unroll
        for (int kt = 0; kt < 4; ++kt) {
            half4 p0, p1;
#pragma unroll
            for (int r = 0; r < 4; ++r) {
                p0[r] = (f16)__builtin_amdgcn_exp2f(s0[kt][r]);
                p1[r] = (f16)__builtin_amdgcn_exp2f(s1[kt][r]);
            }
            pb[0][kt] = p0;
            pb[1][kt] = p1;
        }
#pragma unroll
        for (int kt = 0; kt < 4; ++kt) {
            lacc[0] = __builtin_amdgcn_mfma_f32_16x16x16f16(ones, pb[0][kt], lacc[0], 0, 0, 0);
            lacc[1] = __builtin_amdgcn_mfma_f32_16x16x16f16(ones, pb[1][kt], lacc[1], 0, 0, 0);
#pragma unroll
            for (int dt = 0; dt < 4; ++dt) {
                half4 av = *(const half4*)&Vs[(dt * 16 + l15) * 72 + kt * 16 + quad * 4];
                ot[0][dt] = __builtin_amdgcn_mfma_f32_16x16x16f16(av, pb[0][kt], ot[0][dt], 0, 0, 0);
                ot[1][dt] = __builtin_amdgcn_mfma_f32_16x16x16f16(av, pb[1][kt], ot[1][dt], 0, 0, 0);
            }
        }
    }
    size_t rowbase = ((size_t)chunk * (BB * HEADS) + bh) * NN;
#pragma unroll
    for (int qt = 0; qt < 2; ++qt) {
        if (quad == 0) pl[rowbase + n0 + w * 32 + qt * 16 + l15] = lacc[qt][0];
    }
    __syncthreads();
    f16* T = KV + w * 2304;
#pragma unroll
    for (int qt = 0; qt < 2; ++qt)
#pragma unroll
        for (int dt = 0; dt < 4; ++dt) {
            half4 hv;
#pragma unroll
            for (int r = 0; r < 4; ++r) hv[r] = (f16)ot[qt][dt][r];
            *(half4*)&T[(qt * 16 + l15) * 72 + dt * 16 + quad * 4] = hv;
        }
    __syncthreads();
#pragma unroll
    for (int j = 0; j < 4; ++j) {
        int nl = j * 8 + (lane >> 3);
        int d8 = (lane & 7) * 8;
        half8 v = *(const half8*)&T[nl * 72 + d8];
        *(half8*)&po[(rowbase + n0 + w * 32 + nl) * HD + d8] = v;
    }
}

// ---------------- proj GEMM 128x64 with FUSED chunk-combine + bias + residual ----------------
// A[m][k] = (sum_chunks po[chunk][b*8+h][n][d]) * invl[h][m]  (h = k>>6 = kk>>1, uniform per kk)
__global__ __launch_bounds__(256) void gemm_proj(const f16* __restrict__ po,
                                                 const float* __restrict__ pl,
                                                 const f16* __restrict__ wt,
                                                 const float* __restrict__ x,
                                                 const float* __restrict__ bias,
                                                 float* __restrict__ out) {
    __shared__ __align__(16) f16 As[128 * 32];
    __shared__ __align__(16) f16 Bs[64 * 32];
    __shared__ float invl[HEADS * 128];      // [h][row]
    int tid = threadIdx.x;
    int w = tid >> 6, lane = tid & 63, l15 = lane & 15, quad = lane >> 4;
    int m0 = blockIdx.y * 128, c0 = blockIdx.x * 64;
    int bblk = m0 >> 11;                     // batch uniform per block
    int nbase = m0 & 2047;
    const size_t CSE = (size_t)(BB * HEADS) * NN;      // chunk stride in po/pl rows
    // precompute invl: 1024 entries, 4 per thread
#pragma unroll
    for (int e = 0; e < 4; ++e) {
        int idx = tid + e * 256;             // idx = h*128 + row
        int h = idx >> 7, row = idx & 127;
        size_t prow = (size_t)(bblk * HEADS + h) * NN + nbase + row;
        float l = 0.f;
#pragma unroll
        for (int c = 0; c < NCHUNK; ++c) l += pl[prow + c * CSE];
        invl[idx] = 1.0f / l;
    }
    const char* Bg = (const char*)(wt + (size_t)c0 * DIMC);
    f32x4 acc[2][4] = {};
    int off0 = w * 1024 + lane * 16;
    int offB = tid * 16;
    int rB = offB >> 6, cB = offB & 63;
    __syncthreads();                         // invl ready
    for (int kk = 0; kk < 16; ++kk) {
        int h = kk >> 1;
        // load + combine the A-staging data BEFORE the barrier section
        half8 av[2];
#pragma unroll
        for (int c = 0; c < 2; ++c) {
            int off = c * 4096 + off0;
            int row = off >> 6;
            int colh = (off & 63) >> 1;          // 0..31
            int d = (kk & 1) * 32 + colh;
            size_t pobase = (((size_t)(bblk * HEADS + h) * NN) + nbase + row) * HD + d;
            float s[8] = {};
#pragma unroll
            for (int c4 = 0; c4 < NCHUNK; ++c4) {
                half8 v = *(const half8*)&po[pobase + (size_t)c4 * CSE * HD];
#pragma unroll
                for (int j = 0; j < 8; ++j) s[j] += (float)v[j];
            }
            float il = invl[h * 128 + row];
            half8 o8;
#pragma unroll
            for (int j = 0; j < 8; ++j) o8[j] = (f16)(s[j] * il);
            av[c] = o8;
        }
        __syncthreads();
#pragma unroll
        for (int c = 0; c < 2; ++c)
            *(half8*)((char*)As + c * 4096 + off0) = av[c];
        {
            g2l16(Bg + (size_t)rB * 1024 + kk * 64 + cB, (char*)Bs + w * 1024);
        }
        __syncthreads();
        half8 af[2], bf[4];
#pragma unroll
        for (int i = 0; i < 2; ++i)
            af[i] = *(const half8*)((const char*)As + ((w * 32 + i * 16 + l15) << 6) + quad * 16);
#pragma unroll
        for (int j = 0; j < 4; ++j)
            bf[j] = *(const half8*)((const char*)Bs + ((j * 16 + l15) << 6) + quad * 16);
#pragma unroll
        for (int i = 0; i < 2; ++i)
#pragma unroll
            for (int j = 0; j < 4; ++j)
                acc[i][j] = __builtin_amdgcn_mfma_f32_16x16x32_f16(af[i], bf[j], acc[i][j], 0, 0, 0);
    }
#pragma unroll
    for (int i = 0; i < 2; ++i)
#pragma unroll
        for (int j = 0; j < 4; ++j)
#pragma unroll
            for (int r = 0; r < 4; ++r) {
                int m = m0 + w * 32 + i * 16 + quad * 4 + r;
                int c = c0 + j * 16 + l15;
                out[(size_t)m * DIMC + c] = x[(size_t)m * DIMC + c] + bias[c] + acc[i][j][r];
            }
}

extern "C" void kernel_launch(void* const* d_in, const int* in_sizes, int n_in,
                              void* d_out, int out_size, void* d_ws, size_t ws_size,
                              hipStream_t stream) {
    (void)in_sizes; (void)n_in; (void)out_size; (void)ws_size;
    const float* x     = (const float*)d_in[0];
    const float* wqkv  = (const float*)d_in[1];
    const float* wproj = (const float*)d_in[2];
    const float* bproj = (const float*)d_in[3];
    const float* gamma = (const float*)d_in[4];
    const float* beta  = (const float*)d_in[5];
    float* out = (float*)d_out;

    char* ws = (char*)d_ws;
    f16* xn     = (f16*)ws;                 ws += (size_t)MM * DIMC * 2;
    f16* wqkvt  = (f16*)ws;                 ws += (size_t)NQKV * DIMC * 2;
    f16* wprojt = (f16*)ws;                 ws += (size_t)DIMC * DIMC * 2;
    f16* qbuf   = (f16*)ws;                 ws += (size_t)MM * DIMC * 2;
    f16* kbuf   = (f16*)ws;                 ws += (size_t)MM * DIMC * 2;
    f16* vtbuf  = (f16*)ws;                 ws += (size_t)MM * DIMC * 2;
    f16* po     = (f16*)ws;                 ws += (size_t)NCHUNK * BB * HEADS * NN * HD * 2;
    float* pl   = (float*)ws;               ws += (size_t)NCHUNK * BB * HEADS * NN * sizeof(float);

    prep_kernel<<<2048 + 384 + 128, 256, 0, stream>>>(x, gamma, beta, wqkv, wproj,
                                                      xn, wqkvt, wprojt);
    gemm_qkv<<<dim3(NQKV / 128, MM / 128), 256, 0, stream>>>(xn, wqkvt, qbuf, kbuf, vtbuf);
    attn_kernel<<<NN / 128 * BB * HEADS * NCHUNK, 256, 0, stream>>>(qbuf, kbuf, vtbuf, po, pl);
    gemm_proj<<<dim3(DIMC / 64, MM / 128), 256, 0, stream>>>(po, pl, wprojt, x, bproj, out);
}

// Round 14
// 167.560 us; speedup vs baseline: 1.2305x; 1.2305x over previous
//
#include <hip/hip_runtime.h>
#include <hip/hip_bf16.h>
#include <math.h>

typedef _Float16 f16;
typedef _Float16 half8 __attribute__((ext_vector_type(8)));
typedef _Float16 half4 __attribute__((ext_vector_type(4)));
typedef float f32x4 __attribute__((ext_vector_type(4)));

#define DIMC 512
#define HEADS 8
#define HD 64
#define BB 4
#define NN 2048
#define MM (BB*NN)        // 8192
#define NQKV (3*DIMC)     // 1536
#define SCALE 0.125f
#define LOG2E 1.44269504f
#define EPSLN 1e-5f
#define NCHUNK 2

__device__ __forceinline__ void g2l16(const void* g, void* l) {
    __builtin_amdgcn_global_load_lds(
        (const __attribute__((address_space(1))) unsigned int*)g,
        (__attribute__((address_space(3))) unsigned int*)l, 16, 0, 0);
}

// ---------------- prep: LayerNorm (blocks 0..2047) + weight transposes ----------------
__device__ __forceinline__ void ln_rows(const float* __restrict__ x,
                                        const float* __restrict__ gamma,
                                        const float* __restrict__ beta,
                                        f16* __restrict__ xn, int blk) {
    int w = threadIdx.x >> 6;
    int lane = threadIdx.x & 63;
    int row = blk * 4 + w;
    const float* xr = x + (size_t)row * DIMC;
    float4 v0 = ((const float4*)xr)[lane * 2];
    float4 v1 = ((const float4*)xr)[lane * 2 + 1];
    float s = v0.x + v0.y + v0.z + v0.w + v1.x + v1.y + v1.z + v1.w;
#pragma unroll
    for (int off = 1; off < 64; off <<= 1) s += __shfl_xor(s, off);
    float mu = s * (1.0f / DIMC);
    float d0 = v0.x - mu, d1 = v0.y - mu, d2 = v0.z - mu, d3 = v0.w - mu;
    float d4 = v1.x - mu, d5 = v1.y - mu, d6 = v1.z - mu, d7 = v1.w - mu;
    float s2 = d0*d0 + d1*d1 + d2*d2 + d3*d3 + d4*d4 + d5*d5 + d6*d6 + d7*d7;
#pragma unroll
    for (int off = 1; off < 64; off <<= 1) s2 += __shfl_xor(s2, off);
    float rstd = rsqrtf(s2 * (1.0f / DIMC) + EPSLN);
    float4 g0 = ((const float4*)gamma)[lane * 2];
    float4 g1 = ((const float4*)gamma)[lane * 2 + 1];
    float4 b0 = ((const float4*)beta)[lane * 2];
    float4 b1 = ((const float4*)beta)[lane * 2 + 1];
    half8 o;
    o[0] = (f16)(d0 * rstd * g0.x + b0.x);
    o[1] = (f16)(d1 * rstd * g0.y + b0.y);
    o[2] = (f16)(d2 * rstd * g0.z + b0.z);
    o[3] = (f16)(d3 * rstd * g0.w + b0.w);
    o[4] = (f16)(d4 * rstd * g1.x + b1.x);
    o[5] = (f16)(d5 * rstd * g1.y + b1.y);
    o[6] = (f16)(d6 * rstd * g1.z + b1.z);
    o[7] = (f16)(d7 * rstd * g1.w + b1.w);
    ((half8*)(xn + (size_t)row * DIMC))[lane] = o;
}

__device__ __forceinline__ void transp_tile(const float* __restrict__ src,
                                            f16* __restrict__ dst,
                                            int R, int C, int k0, int n0) {
    __shared__ f16 t[32][72];
    int tid = threadIdx.x;
    int rr = tid >> 6, col = tid & 63;
#pragma unroll
    for (int p = 0; p < 8; p++) {
        int r = p * 4 + rr;
        t[r][col] = (f16)src[(size_t)(k0 + r) * C + n0 + col];
    }
    __syncthreads();
    int nl = tid >> 2, kc = (tid & 3) * 8;
    half8 v;
#pragma unroll
    for (int j = 0; j < 8; j++) v[j] = t[kc + j][nl];
    *(half8*)&dst[(size_t)(n0 + nl) * R + k0 + kc] = v;
}

__global__ __launch_bounds__(256) void prep_kernel(const float* __restrict__ x,
                                                   const float* __restrict__ gamma,
                                                   const float* __restrict__ beta,
                                                   const float* __restrict__ wqkv,
                                                   const float* __restrict__ wproj,
                                                   f16* __restrict__ xn,
                                                   f16* __restrict__ wqkvt,
                                                   f16* __restrict__ wprojt) {
    int bid = blockIdx.x;
    if (bid < 2048) {
        ln_rows(x, gamma, beta, xn, bid);
    } else if (bid < 2048 + 384) {
        int b2 = bid - 2048;
        int bx = b2 % 24, by = b2 / 24;
        transp_tile(wqkv, wqkvt, DIMC, NQKV, by * 32, bx * 64);
    } else {
        int b2 = bid - 2048 - 384;
        int bx = b2 % 8, by = b2 / 8;
        transp_tile(wproj, wprojt, DIMC, DIMC, by * 32, bx * 64);
    }
}

// ---------------- shared 128x128 GEMM mainloop (BK=32, g2l16 — R9 proven) ----------------
__device__ __forceinline__ void gemm128_loop(const char* Ag, const char* Bg,
                                             f16* As, f16* Bs, f32x4 (&acc)[4][4]) {
    int tid = threadIdx.x;
    int w = tid >> 6, lane = tid & 63, l15 = lane & 15, quad = lane >> 4;
    int wy = w >> 1, wx = w & 1;
    int off0 = w * 1024 + lane * 16;
    for (int kk = 0; kk < 16; ++kk) {
        __syncthreads();
#pragma unroll
        for (int c = 0; c < 2; ++c) {
            int off = c * 4096 + off0;
            int row = off >> 6, col = off & 63;
            g2l16(Ag + (size_t)row * 1024 + kk * 64 + col, (char*)As + c * 4096 + w * 1024);
            g2l16(Bg + (size_t)row * 1024 + kk * 64 + col, (char*)Bs + c * 4096 + w * 1024);
        }
        __syncthreads();
        half8 af[4], bf[4];
#pragma unroll
        for (int i = 0; i < 4; ++i) {
            af[i] = *(const half8*)((const char*)As + ((wy * 64 + i * 16 + l15) << 6) + quad * 16);
            bf[i] = *(const half8*)((const char*)Bs + ((wx * 64 + i * 16 + l15) << 6) + quad * 16);
        }
#pragma unroll
        for (int i = 0; i < 4; ++i)
#pragma unroll
            for (int j = 0; j < 4; ++j)
                acc[i][j] = __builtin_amdgcn_mfma_f32_16x16x32_f16(af[i], bf[j], acc[i][j], 0, 0, 0);
    }
}

// ---------------- QKV GEMM 128x128; Q/K direct stores, V via LDS transpose ----------------
__global__ __launch_bounds__(256) void gemm_qkv(const f16* __restrict__ xn,
                                                const f16* __restrict__ wt,
                                                f16* __restrict__ qb,
                                                f16* __restrict__ kbuf,
                                                f16* __restrict__ vtb) {
    __shared__ __align__(16) f16 As[128 * 32];
    __shared__ __align__(16) f16 Bs[128 * 32];
    int tid = threadIdx.x;
    int w = tid >> 6, lane = tid & 63, l15 = lane & 15, quad = lane >> 4;
    int wy = w >> 1, wx = w & 1;
    int m0 = blockIdx.y * 128, c0 = blockIdx.x * 128;
    f32x4 acc[4][4] = {};
    gemm128_loop((const char*)(xn + (size_t)m0 * DIMC),
                 (const char*)(wt + (size_t)c0 * DIMC), As, Bs, acc);
    int bx = blockIdx.x;
    if (bx < 8) {
        const float QS = SCALE * LOG2E;
        f16* dst = (bx < 4) ? qb : kbuf;
        float mul = (bx < 4) ? QS : 1.0f;
        int cb = (bx < 4) ? c0 : c0 - DIMC;
#pragma unroll
        for (int i = 0; i < 4; ++i)
#pragma unroll
            for (int j = 0; j < 4; ++j)
#pragma unroll
                for (int r = 0; r < 4; ++r) {
                    int m = m0 + wy * 64 + i * 16 + quad * 4 + r;
                    int c = cb + wx * 64 + j * 16 + l15;
                    int b = m >> 11, n = m & 2047;
                    int h = c >> 6, d = c & 63;
                    dst[(((size_t)(b * HEADS + h)) * NN + n) * HD + d] = (f16)(acc[i][j][r] * mul);
                }
    } else {
        __syncthreads();
        f16* T = (f16*)As + w * 512;
        int cb = c0 - 2 * DIMC;
        int dl = lane >> 2, mp = lane & 3;
#pragma unroll
        for (int i = 0; i < 4; ++i)
#pragma unroll
            for (int j = 0; j < 4; ++j) {
                half4 hv;
#pragma unroll
                for (int r = 0; r < 4; ++r) hv[r] = (f16)acc[i][j][r];
                *(half4*)&T[l15 * 20 + quad * 4] = hv;
                half4 rv = *(half4*)&T[dl * 20 + mp * 4];
                int c = cb + wx * 64 + j * 16 + dl;
                int m = m0 + wy * 64 + i * 16 + mp * 4;
                int b = m >> 11, n = m & 2047;
                int h = c >> 6, d = c & 63;
                *(half4*)&vtb[(((size_t)(b * HEADS + h)) * HD + d) * NN + n] = rv;
            }
    }
}

// ---------------- Flash attention: K-split x2, fixed-base softmax, XCD-swizzled ----------------
// grid 1024: 64 (bh,chunk) groups x 16 q-tiles; groups striped across XCDs so
// each 256 KB K/V chunk is fetched into one XCD's L2 and reused by 16 blocks.
__global__ __launch_bounds__(256, 4) void attn_kernel(const f16* __restrict__ qb,
                                                      const f16* __restrict__ kbuf,
                                                      const f16* __restrict__ vtb,
                                                      f16* __restrict__ po,
                                                      float* __restrict__ pl) {
    __shared__ __align__(16) f16 KV[9216];   // Ks[64*72] ++ Vs[64*72]
    f16* Ks = KV;
    f16* Vs = KV + 4608;
    int id = blockIdx.x;
    int xcd = id & 7, slot = id >> 3;        // slot 0..127
    int g = xcd * 8 + (slot >> 4);           // 0..63 = (chunk, bh)
    int qt4 = slot & 15;                     // q-tile 0..15
    int bh = g & 31;
    int chunk = g >> 5;
    int n0 = qt4 * 128;
    int tid = threadIdx.x, w = tid >> 6, lane = tid & 63, l15 = lane & 15, quad = lane >> 4;
    const f16* Kbase = kbuf + (size_t)bh * NN * HD;
    const f16* Vbase = vtb + (size_t)bh * HD * NN;
    const f16* Qbase = qb + (size_t)bh * NN * HD;
    half8 qf[2][2];
#pragma unroll
    for (int qt = 0; qt < 2; ++qt) {
        const f16* qr = Qbase + (size_t)(n0 + w * 32 + qt * 16 + l15) * HD + quad * 8;
        qf[qt][0] = *(const half8*)qr;
        qf[qt][1] = *(const half8*)(qr + 32);
    }
    f32x4 ot[2][4] = {};
    f32x4 lacc[2] = {};
    half4 ones;
#pragma unroll
    for (int j = 0; j < 4; ++j) ones[j] = (f16)1.0f;
    int srow = tid >> 2, part = (tid & 3) * 16;
    int kbeg = chunk * (NN / NCHUNK);
    half8 kp0, kp1, vp0, vp1;
    {
        const f16* kg = Kbase + (size_t)(kbeg + srow) * HD + part;
        kp0 = ((const half8*)kg)[0]; kp1 = ((const half8*)kg)[1];
        const f16* vg = Vbase + (size_t)srow * NN + kbeg + part;
        vp0 = ((const half8*)vg)[0]; vp1 = ((const half8*)vg)[1];
    }
    for (int it = 0; it < NN / NCHUNK / 64; ++it) {
        __syncthreads();
        *(half8*)&Ks[srow * 72 + part] = kp0;
        *(half8*)&Ks[srow * 72 + part + 8] = kp1;
        *(half8*)&Vs[srow * 72 + part] = vp0;
        *(half8*)&Vs[srow * 72 + part + 8] = vp1;
        __syncthreads();
        if (it < NN / NCHUNK / 64 - 1) {
            int kt0 = kbeg + (it + 1) * 64;
            const f16* kg = Kbase + (size_t)(kt0 + srow) * HD + part;
            kp0 = ((const half8*)kg)[0]; kp1 = ((const half8*)kg)[1];
            const f16* vg = Vbase + (size_t)srow * NN + kt0 + part;
            vp0 = ((const half8*)vg)[0]; vp1 = ((const half8*)vg)[1];
        }
        f32x4 s0[4], s1[4];
#pragma unroll
        for (int kt = 0; kt < 4; ++kt) {
            half8 a0 = *(const half8*)&Ks[(kt * 16 + l15) * 72 + quad * 8];
            half8 a1 = *(const half8*)&Ks[(kt * 16 + l15) * 72 + 32 + quad * 8];
            f32x4 z0 = {};
            z0 = __builtin_amdgcn_mfma_f32_16x16x32_f16(a0, qf[0][0], z0, 0, 0, 0);
            z0 = __builtin_amdgcn_mfma_f32_16x16x32_f16(a1, qf[0][1], z0, 0, 0, 0);
            s0[kt] = z0;
            f32x4 z1 = {};
            z1 = __builtin_amdgcn_mfma_f32_16x16x32_f16(a0, qf[1][0], z1, 0, 0, 0);
            z1 = __builtin_amdgcn_mfma_f32_16x16x32_f16(a1, qf[1][1], z1, 0, 0, 0);
            s1[kt] = z1;
        }
        half4 pb[2][4];
#pragma unroll
        for (int kt = 0; kt < 4; ++kt) {
            half4 p0, p1;
#pragma unroll
            for (int r = 0; r < 4; ++r) {
                p0[r] = (f16)__builtin_amdgcn_exp2f(s0[kt][r]);
                p1[r] = (f16)__builtin_amdgcn_exp2f(s1[kt][r]);
            }
            pb[0][kt] = p0;
            pb[1][kt] = p1;
        }
#pragma unroll
        for (int kt = 0; kt < 4; ++kt) {
            lacc[0] = __builtin_amdgcn_mfma_f32_16x16x16f16(ones, pb[0][kt], lacc[0], 0, 0, 0);
            lacc[1] = __builtin_amdgcn_mfma_f32_16x16x16f16(ones, pb[1][kt], lacc[1], 0, 0, 0);
#pragma unroll
            for (int dt = 0; dt < 4; ++dt) {
                half4 av = *(const half4*)&Vs[(dt * 16 + l15) * 72 + kt * 16 + quad * 4];
                ot[0][dt] = __builtin_amdgcn_mfma_f32_16x16x16f16(av, pb[0][kt], ot[0][dt], 0, 0, 0);
                ot[1][dt] = __builtin_amdgcn_mfma_f32_16x16x16f16(av, pb[1][kt], ot[1][dt], 0, 0, 0);
            }
        }
    }
    size_t rowbase = ((size_t)chunk * (BB * HEADS) + bh) * NN;
#pragma unroll
    for (int qt = 0; qt < 2; ++qt) {
        if (quad == 0) pl[rowbase + n0 + w * 32 + qt * 16 + l15] = lacc[qt][0];
    }
    __syncthreads();
    f16* T = KV + w * 2304;
#pragma unroll
    for (int qt = 0; qt < 2; ++qt)
#pragma unroll
        for (int dt = 0; dt < 4; ++dt) {
            half4 hv;
#pragma unroll
            for (int r = 0; r < 4; ++r) hv[r] = (f16)ot[qt][dt][r];
            *(half4*)&T[(qt * 16 + l15) * 72 + dt * 16 + quad * 4] = hv;
        }
    __syncthreads();
#pragma unroll
    for (int j = 0; j < 4; ++j) {
        int nl = j * 8 + (lane >> 3);
        int d8 = (lane & 7) * 8;
        half8 v = *(const half8*)&T[nl * 72 + d8];
        *(half8*)&po[(rowbase + n0 + w * 32 + nl) * HD + d8] = v;
    }
}

// ---------------- combine NCHUNK K-chunks: plain sum ----------------
__global__ __launch_bounds__(256) void attn_combine(const f16* __restrict__ po,
                                                    const float* __restrict__ pl,
                                                    f16* __restrict__ ao) {
    int gid = blockIdx.x * 256 + threadIdx.x;
    int row = gid >> 3, d0 = (gid & 7) * 8;
    int bh = row >> 11, n = row & 2047;
    const int CS = BB * HEADS * NN;
    float l = 0.f;
#pragma unroll
    for (int c = 0; c < NCHUNK; ++c) l += pl[row + c * CS];
    float inv = 1.0f / l;
    float acc[8] = {};
#pragma unroll
    for (int c = 0; c < NCHUNK; ++c) {
        half8 oc = *(const half8*)&po[((size_t)row + c * CS) * HD + d0];
#pragma unroll
        for (int j = 0; j < 8; ++j) acc[j] += (float)oc[j];
    }
    half8 r;
#pragma unroll
    for (int j = 0; j < 8; ++j) r[j] = (f16)(acc[j] * inv);
    int h = bh & 7, b = bh >> 3;
    *(half8*)&ao[((size_t)(b * NN + n)) * DIMC + h * HD + d0] = r;
}

// ---------------- proj GEMM 128x64 + bias + residual (g2l16 — R12 proven) ----------------
__global__ __launch_bounds__(256) void gemm_proj(const f16* __restrict__ aob,
                                                 const f16* __restrict__ wt,
                                                 const float* __restrict__ x,
                                                 const float* __restrict__ bias,
                                                 float* __restrict__ out) {
    __shared__ __align__(16) f16 As[128 * 32];
    __shared__ __align__(16) f16 Bs[64 * 32];
    int tid = threadIdx.x;
    int w = tid >> 6, lane = tid & 63, l15 = lane & 15, quad = lane >> 4;
    int m0 = blockIdx.y * 128, c0 = blockIdx.x * 64;
    const char* Ag = (const char*)(aob + (size_t)m0 * DIMC);
    const char* Bg = (const char*)(wt + (size_t)c0 * DIMC);
    f32x4 acc[2][4] = {};
    int off0 = w * 1024 + lane * 16;
    for (int kk = 0; kk < 16; ++kk) {
        __syncthreads();
#pragma unroll
        for (int c = 0; c < 2; ++c) {
            int off = c * 4096 + off0;
            int row = off >> 6, col = off & 63;
            g2l16(Ag + (size_t)row * 1024 + kk * 64 + col, (char*)As + c * 4096 + w * 1024);
        }
        {
            int off = tid * 16;
            int row = off >> 6, col = off & 63;
            g2l16(Bg + (size_t)row * 1024 + kk * 64 + col, (char*)Bs + w * 1024);
        }
        __syncthreads();
        half8 af[2], bf[4];
#pragma unroll
        for (int i = 0; i < 2; ++i)
            af[i] = *(const half8*)((const char*)As + ((w * 32 + i * 16 + l15) << 6) + quad * 16);
#pragma unroll
        for (int j = 0; j < 4; ++j)
            bf[j] = *(const half8*)((const char*)Bs + ((j * 16 + l15) << 6) + quad * 16);
#pragma unroll
        for (int i = 0; i < 2; ++i)
#pragma unroll
            for (int j = 0; j < 4; ++j)
                acc[i][j] = __builtin_amdgcn_mfma_f32_16x16x32_f16(af[i], bf[j], acc[i][j], 0, 0, 0);
    }
#pragma unroll
    for (int i = 0; i < 2; ++i)
#pragma unroll
        for (int j = 0; j < 4; ++j)
#pragma unroll
            for (int r = 0; r < 4; ++r) {
                int m = m0 + w * 32 + i * 16 + quad * 4 + r;
                int c = c0 + j * 16 + l15;
                out[(size_t)m * DIMC + c] = x[(size_t)m * DIMC + c] + bias[c] + acc[i][j][r];
            }
}

extern "C" void kernel_launch(void* const* d_in, const int* in_sizes, int n_in,
                              void* d_out, int out_size, void* d_ws, size_t ws_size,
                              hipStream_t stream) {
    (void)in_sizes; (void)n_in; (void)out_size; (void)ws_size;
    const float* x     = (const float*)d_in[0];
    const float* wqkv  = (const float*)d_in[1];
    const float* wproj = (const float*)d_in[2];
    const float* bproj = (const float*)d_in[3];
    const float* gamma = (const float*)d_in[4];
    const float* beta  = (const float*)d_in[5];
    float* out = (float*)d_out;

    char* ws = (char*)d_ws;
    f16* xn     = (f16*)ws;                 ws += (size_t)MM * DIMC * 2;
    f16* wqkvt  = (f16*)ws;                 ws += (size_t)NQKV * DIMC * 2;
    f16* wprojt = (f16*)ws;                 ws += (size_t)DIMC * DIMC * 2;
    f16* qbuf   = (f16*)ws;                 ws += (size_t)MM * DIMC * 2;
    f16* kbuf   = (f16*)ws;                 ws += (size_t)MM * DIMC * 2;
    f16* vtbuf  = (f16*)ws;                 ws += (size_t)MM * DIMC * 2;
    f16* aobuf  = (f16*)ws;                 ws += (size_t)MM * DIMC * 2;
    f16* po     = (f16*)ws;                 ws += (size_t)NCHUNK * BB * HEADS * NN * HD * 2;
    float* pl   = (float*)ws;               ws += (size_t)NCHUNK * BB * HEADS * NN * sizeof(float);

    prep_kernel<<<2048 + 384 + 128, 256, 0, stream>>>(x, gamma, beta, wqkv, wproj,
                                                      xn, wqkvt, wprojt);
    gemm_qkv<<<dim3(NQKV / 128, MM / 128), 256, 0, stream>>>(xn, wqkvt, qbuf, kbuf, vtbuf);
    attn_kernel<<<NN / 128 * BB * HEADS * NCHUNK, 256, 0, stream>>>(qbuf, kbuf, vtbuf, po, pl);
    attn_combine<<<(BB * HEADS * NN * HD / 8) / 256, 256, 0, stream>>>(po, pl, aobuf);
    gemm_proj<<<dim3(DIMC / 64, MM / 128), 256, 0, stream>>>(aobuf, wprojt, x, bproj, out);
}

// Round 15
// 164.809 us; speedup vs baseline: 1.2511x; 1.0167x over previous
//
#include <hip/hip_runtime.h>
#include <hip/hip_bf16.h>
#include <math.h>

typedef _Float16 f16;
typedef _Float16 half8 __attribute__((ext_vector_type(8)));
typedef _Float16 half4 __attribute__((ext_vector_type(4)));
typedef float f32x4 __attribute__((ext_vector_type(4)));

#define DIMC 512
#define HEADS 8
#define HD 64
#define BB 4
#define NN 2048
#define MM (BB*NN)        // 8192
#define NQKV (3*DIMC)     // 1536
#define SCALE 0.125f
#define LOG2E 1.44269504f
#define EPSLN 1e-5f
#define NCHUNK 2

__device__ __forceinline__ void g2l16(const void* g, void* l) {
    __builtin_amdgcn_global_load_lds(
        (const __attribute__((address_space(1))) unsigned int*)g,
        (__attribute__((address_space(3))) unsigned int*)l, 16, 0, 0);
}

// ---------------- prep: LayerNorm (blocks 0..2047) + weight transposes ----------------
__device__ __forceinline__ void ln_rows(const float* __restrict__ x,
                                        const float* __restrict__ gamma,
                                        const float* __restrict__ beta,
                                        f16* __restrict__ xn, int blk) {
    int w = threadIdx.x >> 6;
    int lane = threadIdx.x & 63;
    int row = blk * 4 + w;
    const float* xr = x + (size_t)row * DIMC;
    float4 v0 = ((const float4*)xr)[lane * 2];
    float4 v1 = ((const float4*)xr)[lane * 2 + 1];
    float s = v0.x + v0.y + v0.z + v0.w + v1.x + v1.y + v1.z + v1.w;
#pragma unroll
    for (int off = 1; off < 64; off <<= 1) s += __shfl_xor(s, off);
    float mu = s * (1.0f / DIMC);
    float d0 = v0.x - mu, d1 = v0.y - mu, d2 = v0.z - mu, d3 = v0.w - mu;
    float d4 = v1.x - mu, d5 = v1.y - mu, d6 = v1.z - mu, d7 = v1.w - mu;
    float s2 = d0*d0 + d1*d1 + d2*d2 + d3*d3 + d4*d4 + d5*d5 + d6*d6 + d7*d7;
#pragma unroll
    for (int off = 1; off < 64; off <<= 1) s2 += __shfl_xor(s2, off);
    float rstd = rsqrtf(s2 * (1.0f / DIMC) + EPSLN);
    float4 g0 = ((const float4*)gamma)[lane * 2];
    float4 g1 = ((const float4*)gamma)[lane * 2 + 1];
    float4 b0 = ((const float4*)beta)[lane * 2];
    float4 b1 = ((const float4*)beta)[lane * 2 + 1];
    half8 o;
    o[0] = (f16)(d0 * rstd * g0.x + b0.x);
    o[1] = (f16)(d1 * rstd * g0.y + b0.y);
    o[2] = (f16)(d2 * rstd * g0.z + b0.z);
    o[3] = (f16)(d3 * rstd * g0.w + b0.w);
    o[4] = (f16)(d4 * rstd * g1.x + b1.x);
    o[5] = (f16)(d5 * rstd * g1.y + b1.y);
    o[6] = (f16)(d6 * rstd * g1.z + b1.z);
    o[7] = (f16)(d7 * rstd * g1.w + b1.w);
    ((half8*)(xn + (size_t)row * DIMC))[lane] = o;
}

__device__ __forceinline__ void transp_tile(const float* __restrict__ src,
                                            f16* __restrict__ dst,
                                            int R, int C, int k0, int n0) {
    __shared__ f16 t[32][72];
    int tid = threadIdx.x;
    int rr = tid >> 6, col = tid & 63;
#pragma unroll
    for (int p = 0; p < 8; p++) {
        int r = p * 4 + rr;
        t[r][col] = (f16)src[(size_t)(k0 + r) * C + n0 + col];
    }
    __syncthreads();
    int nl = tid >> 2, kc = (tid & 3) * 8;
    half8 v;
#pragma unroll
    for (int j = 0; j < 8; j++) v[j] = t[kc + j][nl];
    *(half8*)&dst[(size_t)(n0 + nl) * R + k0 + kc] = v;
}

__global__ __launch_bounds__(256) void prep_kernel(const float* __restrict__ x,
                                                   const float* __restrict__ gamma,
                                                   const float* __restrict__ beta,
                                                   const float* __restrict__ wqkv,
                                                   const float* __restrict__ wproj,
                                                   f16* __restrict__ xn,
                                                   f16* __restrict__ wqkvt,
                                                   f16* __restrict__ wprojt) {
    int bid = blockIdx.x;
    if (bid < 2048) {
        ln_rows(x, gamma, beta, xn, bid);
    } else if (bid < 2048 + 384) {
        int b2 = bid - 2048;
        int bx = b2 % 24, by = b2 / 24;
        transp_tile(wqkv, wqkvt, DIMC, NQKV, by * 32, bx * 64);
    } else {
        int b2 = bid - 2048 - 384;
        int bx = b2 % 8, by = b2 / 8;
        transp_tile(wproj, wprojt, DIMC, DIMC, by * 32, bx * 64);
    }
}

// ---------------- shared 128x128 GEMM mainloop (BK=32, g2l16 — R9 proven) ----------------
__device__ __forceinline__ void gemm128_loop(const char* Ag, const char* Bg,
                                             f16* As, f16* Bs, f32x4 (&acc)[4][4]) {
    int tid = threadIdx.x;
    int w = tid >> 6, lane = tid & 63, l15 = lane & 15, quad = lane >> 4;
    int wy = w >> 1, wx = w & 1;
    int off0 = w * 1024 + lane * 16;
    for (int kk = 0; kk < 16; ++kk) {
        __syncthreads();
#pragma unroll
        for (int c = 0; c < 2; ++c) {
            int off = c * 4096 + off0;
            int row = off >> 6, col = off & 63;
            g2l16(Ag + (size_t)row * 1024 + kk * 64 + col, (char*)As + c * 4096 + w * 1024);
            g2l16(Bg + (size_t)row * 1024 + kk * 64 + col, (char*)Bs + c * 4096 + w * 1024);
        }
        __syncthreads();
        half8 af[4], bf[4];
#pragma unroll
        for (int i = 0; i < 4; ++i) {
            af[i] = *(const half8*)((const char*)As + ((wy * 64 + i * 16 + l15) << 6) + quad * 16);
            bf[i] = *(const half8*)((const char*)Bs + ((wx * 64 + i * 16 + l15) << 6) + quad * 16);
        }
#pragma unroll
        for (int i = 0; i < 4; ++i)
#pragma unroll
            for (int j = 0; j < 4; ++j)
                acc[i][j] = __builtin_amdgcn_mfma_f32_16x16x32_f16(af[i], bf[j], acc[i][j], 0, 0, 0);
    }
}

// ---------------- QKV GEMM 128x128; Q/K direct stores, V via LDS transpose ----------------
__global__ __launch_bounds__(256) void gemm_qkv(const f16* __restrict__ xn,
                                                const f16* __restrict__ wt,
                                                f16* __restrict__ qb,
                                                f16* __restrict__ kbuf,
                                                f16* __restrict__ vtb) {
    __shared__ __align__(16) f16 As[128 * 32];
    __shared__ __align__(16) f16 Bs[128 * 32];
    int tid = threadIdx.x;
    int w = tid >> 6, lane = tid & 63, l15 = lane & 15, quad = lane >> 4;
    int wy = w >> 1, wx = w & 1;
    int m0 = blockIdx.y * 128, c0 = blockIdx.x * 128;
    f32x4 acc[4][4] = {};
    gemm128_loop((const char*)(xn + (size_t)m0 * DIMC),
                 (const char*)(wt + (size_t)c0 * DIMC), As, Bs, acc);
    int bx = blockIdx.x;
    if (bx < 8) {
        const float QS = SCALE * LOG2E;
        f16* dst = (bx < 4) ? qb : kbuf;
        float mul = (bx < 4) ? QS : 1.0f;
        int cb = (bx < 4) ? c0 : c0 - DIMC;
#pragma unroll
        for (int i = 0; i < 4; ++i)
#pragma unroll
            for (int j = 0; j < 4; ++j)
#pragma unroll
                for (int r = 0; r < 4; ++r) {
                    int m = m0 + wy * 64 + i * 16 + quad * 4 + r;
                    int c = cb + wx * 64 + j * 16 + l15;
                    int b = m >> 11, n = m & 2047;
                    int h = c >> 6, d = c & 63;
                    dst[(((size_t)(b * HEADS + h)) * NN + n) * HD + d] = (f16)(acc[i][j][r] * mul);
                }
    } else {
        __syncthreads();
        f16* T = (f16*)As + w * 512;
        int cb = c0 - 2 * DIMC;
        int dl = lane >> 2, mp = lane & 3;
#pragma unroll
        for (int i = 0; i < 4; ++i)
#pragma unroll
            for (int j = 0; j < 4; ++j) {
                half4 hv;
#pragma unroll
                for (int r = 0; r < 4; ++r) hv[r] = (f16)acc[i][j][r];
                *(half4*)&T[l15 * 20 + quad * 4] = hv;
                half4 rv = *(half4*)&T[dl * 20 + mp * 4];
                int c = cb + wx * 64 + j * 16 + dl;
                int m = m0 + wy * 64 + i * 16 + mp * 4;
                int b = m >> 11, n = m & 2047;
                int h = c >> 6, d = c & 63;
                *(half4*)&vtb[(((size_t)(b * HEADS + h)) * HD + d) * NN + n] = rv;
            }
    }
}

// ---------------- Flash attention: K-split x2, fixed-base softmax, XCD-swizzled ----------------
// PV at K=32 via wave-private P bounce (no barrier): per-iter MFMA 56 -> 36.
__global__ __launch_bounds__(256, 4) void attn_kernel(const f16* __restrict__ qb,
                                                      const f16* __restrict__ kbuf,
                                                      const f16* __restrict__ vtb,
                                                      f16* __restrict__ po,
                                                      float* __restrict__ pl) {
    __shared__ __align__(16) f16 KV[9216];   // Ks[64*72] ++ Vs[64*72]
    __shared__ __align__(16) f16 Pb[4][2304]; // per-wave P: [32 q][72 keys]
    f16* Ks = KV;
    f16* Vs = KV + 4608;
    int id = blockIdx.x;
    int xcd = id & 7, slot = id >> 3;        // slot 0..127
    int g = xcd * 8 + (slot >> 4);           // 0..63 = (chunk, bh)
    int qt4 = slot & 15;                     // q-tile 0..15
    int bh = g & 31;
    int chunk = g >> 5;
    int n0 = qt4 * 128;
    int tid = threadIdx.x, w = tid >> 6, lane = tid & 63, l15 = lane & 15, quad = lane >> 4;
    const f16* Kbase = kbuf + (size_t)bh * NN * HD;
    const f16* Vbase = vtb + (size_t)bh * HD * NN;
    const f16* Qbase = qb + (size_t)bh * NN * HD;
    half8 qf[2][2];
#pragma unroll
    for (int qt = 0; qt < 2; ++qt) {
        const f16* qr = Qbase + (size_t)(n0 + w * 32 + qt * 16 + l15) * HD + quad * 8;
        qf[qt][0] = *(const half8*)qr;
        qf[qt][1] = *(const half8*)(qr + 32);
    }
    f32x4 ot[2][4] = {};
    f32x4 lacc[2] = {};
    half8 ones8;
#pragma unroll
    for (int j = 0; j < 8; ++j) ones8[j] = (f16)1.0f;
    int srow = tid >> 2, part = (tid & 3) * 16;
    int kbeg = chunk * (NN / NCHUNK);
    half8 kp0, kp1, vp0, vp1;
    {
        const f16* kg = Kbase + (size_t)(kbeg + srow) * HD + part;
        kp0 = ((const half8*)kg)[0]; kp1 = ((const half8*)kg)[1];
        const f16* vg = Vbase + (size_t)srow * NN + kbeg + part;
        vp0 = ((const half8*)vg)[0]; vp1 = ((const half8*)vg)[1];
    }
    f16* P = &Pb[w][0];
    for (int it = 0; it < NN / NCHUNK / 64; ++it) {
        __syncthreads();
        *(half8*)&Ks[srow * 72 + part] = kp0;
        *(half8*)&Ks[srow * 72 + part + 8] = kp1;
        *(half8*)&Vs[srow * 72 + part] = vp0;
        *(half8*)&Vs[srow * 72 + part + 8] = vp1;
        __syncthreads();
        if (it < NN / NCHUNK / 64 - 1) {
            int kt0 = kbeg + (it + 1) * 64;
            const f16* kg = Kbase + (size_t)(kt0 + srow) * HD + part;
            kp0 = ((const half8*)kg)[0]; kp1 = ((const half8*)kg)[1];
            const f16* vg = Vbase + (size_t)srow * NN + kt0 + part;
            vp0 = ((const half8*)vg)[0]; vp1 = ((const half8*)vg)[1];
        }
        f32x4 s0[4], s1[4];
#pragma unroll
        for (int kt = 0; kt < 4; ++kt) {
            half8 a0 = *(const half8*)&Ks[(kt * 16 + l15) * 72 + quad * 8];
            half8 a1 = *(const half8*)&Ks[(kt * 16 + l15) * 72 + 32 + quad * 8];
            f32x4 z0 = {};
            z0 = __builtin_amdgcn_mfma_f32_16x16x32_f16(a0, qf[0][0], z0, 0, 0, 0);
            z0 = __builtin_amdgcn_mfma_f32_16x16x32_f16(a1, qf[0][1], z0, 0, 0, 0);
            s0[kt] = z0;
            f32x4 z1 = {};
            z1 = __builtin_amdgcn_mfma_f32_16x16x32_f16(a0, qf[1][0], z1, 0, 0, 0);
            z1 = __builtin_amdgcn_mfma_f32_16x16x32_f16(a1, qf[1][1], z1, 0, 0, 0);
            s1[kt] = z1;
        }
        // exp2 -> wave-private P bounce (C-layout write, B-operand K=32 read)
#pragma unroll
        for (int kt = 0; kt < 4; ++kt) {
            half4 p0, p1;
#pragma unroll
            for (int r = 0; r < 4; ++r) {
                p0[r] = (f16)__builtin_amdgcn_exp2f(s0[kt][r]);
                p1[r] = (f16)__builtin_amdgcn_exp2f(s1[kt][r]);
            }
            *(half4*)&P[(0 * 16 + l15) * 72 + kt * 16 + quad * 4] = p0;
            *(half4*)&P[(1 * 16 + l15) * 72 + kt * 16 + quad * 4] = p1;
        }
        // PV + l-sum at K=32: O^T[d][q] += V^T[d][k]*P^T[k][q]
#pragma unroll
        for (int qt = 0; qt < 2; ++qt)
#pragma unroll
            for (int kc = 0; kc < 2; ++kc) {
                half8 pb8 = *(const half8*)&P[(qt * 16 + l15) * 72 + kc * 32 + quad * 8];
                lacc[qt] = __builtin_amdgcn_mfma_f32_16x16x32_f16(ones8, pb8, lacc[qt], 0, 0, 0);
#pragma unroll
                for (int dt = 0; dt < 4; ++dt) {
                    half8 av = *(const half8*)&Vs[(dt * 16 + l15) * 72 + kc * 32 + quad * 8];
                    ot[qt][dt] = __builtin_amdgcn_mfma_f32_16x16x32_f16(av, pb8, ot[qt][dt], 0, 0, 0);
                }
            }
    }
    size_t rowbase = ((size_t)chunk * (BB * HEADS) + bh) * NN;
#pragma unroll
    for (int qt = 0; qt < 2; ++qt) {
        if (quad == 0) pl[rowbase + n0 + w * 32 + qt * 16 + l15] = lacc[qt][0];
    }
    __syncthreads();
    f16* T = KV + w * 2304;
#pragma unroll
    for (int qt = 0; qt < 2; ++qt)
#pragma unroll
        for (int dt = 0; dt < 4; ++dt) {
            half4 hv;
#pragma unroll
            for (int r = 0; r < 4; ++r) hv[r] = (f16)ot[qt][dt][r];
            *(half4*)&T[(qt * 16 + l15) * 72 + dt * 16 + quad * 4] = hv;
        }
    __syncthreads();
#pragma unroll
    for (int j = 0; j < 4; ++j) {
        int nl = j * 8 + (lane >> 3);
        int d8 = (lane & 7) * 8;
        half8 v = *(const half8*)&T[nl * 72 + d8];
        *(half8*)&po[(rowbase + n0 + w * 32 + nl) * HD + d8] = v;
    }
}

// ---------------- combine NCHUNK K-chunks: plain sum ----------------
__global__ __launch_bounds__(256) void attn_combine(const f16* __restrict__ po,
                                                    const float* __restrict__ pl,
                                                    f16* __restrict__ ao) {
    int gid = blockIdx.x * 256 + threadIdx.x;
    int row = gid >> 3, d0 = (gid & 7) * 8;
    int bh = row >> 11, n = row & 2047;
    const int CS = BB * HEADS * NN;
    float l = 0.f;
#pragma unroll
    for (int c = 0; c < NCHUNK; ++c) l += pl[row + c * CS];
    float inv = 1.0f / l;
    float acc[8] = {};
#pragma unroll
    for (int c = 0; c < NCHUNK; ++c) {
        half8 oc = *(const half8*)&po[((size_t)row + c * CS) * HD + d0];
#pragma unroll
        for (int j = 0; j < 8; ++j) acc[j] += (float)oc[j];
    }
    half8 r;
#pragma unroll
    for (int j = 0; j < 8; ++j) r[j] = (f16)(acc[j] * inv);
    int h = bh & 7, b = bh >> 3;
    *(half8*)&ao[((size_t)(b * NN + n)) * DIMC + h * HD + d0] = r;
}

// ---------------- proj GEMM 128x64 + bias + residual (g2l16 — R12 proven) ----------------
__global__ __launch_bounds__(256) void gemm_proj(const f16* __restrict__ aob,
                                                 const f16* __restrict__ wt,
                                                 const float* __restrict__ x,
                                                 const float* __restrict__ bias,
                                                 float* __restrict__ out) {
    __shared__ __align__(16) f16 As[128 * 32];
    __shared__ __align__(16) f16 Bs[64 * 32];
    int tid = threadIdx.x;
    int w = tid >> 6, lane = tid & 63, l15 = lane & 15, quad = lane >> 4;
    int m0 = blockIdx.y * 128, c0 = blockIdx.x * 64;
    const char* Ag = (const char*)(aob + (size_t)m0 * DIMC);
    const char* Bg = (const char*)(wt + (size_t)c0 * DIMC);
    f32x4 acc[2][4] = {};
    int off0 = w * 1024 + lane * 16;
    for (int kk = 0; kk < 16; ++kk) {
        __syncthreads();
#pragma unroll
        for (int c = 0; c < 2; ++c) {
            int off = c * 4096 + off0;
            int row = off >> 6, col = off & 63;
            g2l16(Ag + (size_t)row * 1024 + kk * 64 + col, (char*)As + c * 4096 + w * 1024);
        }
        {
            int off = tid * 16;
            int row = off >> 6, col = off & 63;
            g2l16(Bg + (size_t)row * 1024 + kk * 64 + col, (char*)Bs + w * 1024);
        }
        __syncthreads();
        half8 af[2], bf[4];
#pragma unroll
        for (int i = 0; i < 2; ++i)
            af[i] = *(const half8*)((const char*)As + ((w * 32 + i * 16 + l15) << 6) + quad * 16);
#pragma unroll
        for (int j = 0; j < 4; ++j)
            bf[j] = *(const half8*)((const char*)Bs + ((j * 16 + l15) << 6) + quad * 16);
#pragma unroll
        for (int i = 0; i < 2; ++i)
#pragma unroll
            for (int j = 0; j < 4; ++j)
                acc[i][j] = __builtin_amdgcn_mfma_f32_16x16x32_f16(af[i], bf[j], acc[i][j], 0, 0, 0);
    }
#pragma unroll
    for (int i = 0; i < 2; ++i)
#pragma unroll
        for (int j = 0; j < 4; ++j)
#pragma unroll
            for (int r = 0; r < 4; ++r) {
                int m = m0 + w * 32 + i * 16 + quad * 4 + r;
                int c = c0 + j * 16 + l15;
                out[(size_t)m * DIMC + c] = x[(size_t)m * DIMC + c] + bias[c] + acc[i][j][r];
            }
}

extern "C" void kernel_launch(void* const* d_in, const int* in_sizes, int n_in,
                              void* d_out, int out_size, void* d_ws, size_t ws_size,
                              hipStream_t stream) {
    (void)in_sizes; (void)n_in; (void)out_size; (void)ws_size;
    const float* x     = (const float*)d_in[0];
    const float* wqkv  = (const float*)d_in[1];
    const float* wproj = (const float*)d_in[2];
    const float* bproj = (const float*)d_in[3];
    const float* gamma = (const float*)d_in[4];
    const float* beta  = (const float*)d_in[5];
    float* out = (float*)d_out;

    char* ws = (char*)d_ws;
    f16* xn     = (f16*)ws;                 ws += (size_t)MM * DIMC * 2;
    f16* wqkvt  = (f16*)ws;                 ws += (size_t)NQKV * DIMC * 2;
    f16* wprojt = (f16*)ws;                 ws += (size_t)DIMC * DIMC * 2;
    f16* qbuf   = (f16*)ws;                 ws += (size_t)MM * DIMC * 2;
    f16* kbuf   = (f16*)ws;                 ws += (size_t)MM * DIMC * 2;
    f16* vtbuf  = (f16*)ws;                 ws += (size_t)MM * DIMC * 2;
    f16* aobuf  = (f16*)ws;                 ws += (size_t)MM * DIMC * 2;
    f16* po     = (f16*)ws;                 ws += (size_t)NCHUNK * BB * HEADS * NN * HD * 2;
    float* pl   = (float*)ws;               ws += (size_t)NCHUNK * BB * HEADS * NN * sizeof(float);

    prep_kernel<<<2048 + 384 + 128, 256, 0, stream>>>(x, gamma, beta, wqkv, wproj,
                                                      xn, wqkvt, wprojt);
    gemm_qkv<<<dim3(NQKV / 128, MM / 128), 256, 0, stream>>>(xn, wqkvt, qbuf, kbuf, vtbuf);
    attn_kernel<<<NN / 128 * BB * HEADS * NCHUNK, 256, 0, stream>>>(qbuf, kbuf, vtbuf, po, pl);
    attn_combine<<<(BB * HEADS * NN * HD / 8) / 256, 256, 0, stream>>>(po, pl, aobuf);
    gemm_proj<<<dim3(DIMC / 64, MM / 128), 256, 0, stream>>>(aobuf, wprojt, x, bproj, out);
}